// Round 10
// baseline (630.828 us; speedup 1.0000x reference)
//
#include <hip/hip_runtime.h>

typedef __attribute__((ext_vector_type(8))) short short8v;
typedef __attribute__((ext_vector_type(4))) short short4v;
typedef __attribute__((ext_vector_type(4))) float float4v;
typedef __attribute__((ext_vector_type(2))) unsigned int uint2v;

#define MFMA16(a,b,c) __builtin_amdgcn_mfma_f32_16x16x32_bf16(a,b,c,0,0,0)

__device__ __forceinline__ unsigned short f2b(float f) {
    union { float f; unsigned u; } v; v.f = f;
    unsigned r = v.u + 0x7FFFu + ((v.u >> 16) & 1u);
    return (unsigned short)(r >> 16);
}
__device__ __forceinline__ float b2f(unsigned short s) {
    union { unsigned u; float f; } v; v.u = ((unsigned)s) << 16;
    return v.f;
}
// RNE f32x8 -> bf16x8 via v_cvt_pk_bf16_f32 (same rounding as f2b)
__device__ __forceinline__ short8v pack8(float4v a, float4v b) {
    union { unsigned u[4]; short8v s; } o;
    asm("v_cvt_pk_bf16_f32 %0, %1, %2" : "=v"(o.u[0]) : "v"(a[0]), "v"(a[1]));
    asm("v_cvt_pk_bf16_f32 %0, %1, %2" : "=v"(o.u[1]) : "v"(a[2]), "v"(a[3]));
    asm("v_cvt_pk_bf16_f32 %0, %1, %2" : "=v"(o.u[2]) : "v"(b[0]), "v"(b[1]));
    asm("v_cvt_pk_bf16_f32 %0, %1, %2" : "=v"(o.u[3]) : "v"(b[2]), "v"(b[3]));
    return o.s;
}

// ---------------------------------------------------------------------------
// P1: consolidated f32 -> bf16 pack for hidden / Wq / Wk / Wv (one launch).
// ---------------------------------------------------------------------------
__global__ __launch_bounds__(256) void pack_all(
    const float* __restrict__ hidden, const float* __restrict__ Wq,
    const float* __restrict__ Wk, const float* __restrict__ Wv,
    unsigned short* __restrict__ hb, unsigned short* __restrict__ Wqb,
    unsigned short* __restrict__ Wkb, unsigned short* __restrict__ Wvb) {
    const int bid = blockIdx.x;
    const float* in; unsigned short* out; int i;
    if (bid < 2048)      { in = hidden; out = hb;  i = bid * 256 + threadIdx.x; }
    else if (bid < 2560) { in = Wq; out = Wqb; i = (bid - 2048) * 256 + threadIdx.x; }
    else if (bid < 3072) { in = Wk; out = Wkb; i = (bid - 2560) * 256 + threadIdx.x; }
    else                 { in = Wv; out = Wvb; i = (bid - 3072) * 256 + threadIdx.x; }
    float4v a = *(const float4v*)&in[(size_t)i * 8];
    float4v b = *(const float4v*)&in[(size_t)i * 8 + 4];
    *(short8v*)&out[(size_t)i * 8] = pack8(a, b);
}

// ---------------------------------------------------------------------------
// P2: C = hb @ W^T + bias  (MFMA bf16, operands direct from global)
// ---------------------------------------------------------------------------
__global__ __launch_bounds__(256) void qkv_gemm(
    const unsigned short* __restrict__ A,   // [4096][1024] bf16
    const unsigned short* __restrict__ W,   // [1024][1024] bf16 [n][k]
    const float* __restrict__ bias,         // [1024]
    unsigned short* __restrict__ out, int vmode) {
    const int wave = threadIdx.x >> 6, lane = threadIdx.x & 63;
    const int m0 = blockIdx.y * 128 + wave * 32;
    const int n0 = blockIdx.x * 64;
    const int lrow = lane & 15, g8 = (lane >> 4) << 3, row4 = (lane >> 4) << 2;
    float4v acc[2][4] = {};
    const unsigned short* Ap = A + (size_t)(m0 + lrow) * 1024 + g8;
    const unsigned short* Wp = W + (size_t)(n0 + lrow) * 1024 + g8;
#pragma unroll 2
    for (int k0 = 0; k0 < 1024; k0 += 32) {
        short8v a0 = *(const short8v*)(Ap + k0);
        short8v a1 = *(const short8v*)(Ap + 16 * 1024 + k0);
        short8v b0 = *(const short8v*)(Wp + k0);
        short8v b1 = *(const short8v*)(Wp + 16 * 1024 + k0);
        short8v b2 = *(const short8v*)(Wp + 32 * 1024 + k0);
        short8v b3 = *(const short8v*)(Wp + 48 * 1024 + k0);
        acc[0][0] = MFMA16(a0, b0, acc[0][0]); acc[0][1] = MFMA16(a0, b1, acc[0][1]);
        acc[0][2] = MFMA16(a0, b2, acc[0][2]); acc[0][3] = MFMA16(a0, b3, acc[0][3]);
        acc[1][0] = MFMA16(a1, b0, acc[1][0]); acc[1][1] = MFMA16(a1, b1, acc[1][1]);
        acc[1][2] = MFMA16(a1, b2, acc[1][2]); acc[1][3] = MFMA16(a1, b3, acc[1][3]);
    }
#pragma unroll
    for (int nt = 0; nt < 4; ++nt) {
        const int n = n0 + nt * 16 + lrow;           // C col = lane&15
        const float bz = bias[n];
        const int h = n >> 6, d = n & 63;
#pragma unroll
        for (int mt = 0; mt < 2; ++mt) {
            const int mb = m0 + mt * 16 + row4;      // C row = (lane>>4)*4 + j
            if (vmode == 0) {
#pragma unroll
                for (int j = 0; j < 4; ++j) {
                    const int m = mb + j;
                    const int b = m >> 10, l = m & 1023;
                    out[(((size_t)(b * 16 + h) << 10) + l) * 64 + d] = f2b(acc[mt][nt][j] + bz);
                }
            } else {
                const int b = mb >> 10, r = mb & 1023;
                short4v pk;
#pragma unroll
                for (int j = 0; j < 4; ++j) pk[j] = (short)f2b(acc[mt][nt][j] + bz);
                *(short4v*)&out[((((size_t)(b * 16 + h)) << 6) + d) * 1024 + r] = pk;
            }
        }
    }
}

// ---------------------------------------------------------------------------
// P3: headproj
// ---------------------------------------------------------------------------
__global__ __launch_bounds__(256) void headproj(
    const unsigned short* __restrict__ xh,  // [64][1024][64] bf16
    const float* __restrict__ Wsx,          // [64][64] f32
    const float* __restrict__ bsx,          // [64]
    unsigned short* __restrict__ x2b,       // [1024][64][64] bf16
    float* __restrict__ xbv) {              // [1024][64]
    __shared__ __align__(16) float Ws[64 * 64];
    __shared__ float bs[64];
    __shared__ __align__(16) unsigned short Xl[64 * 64];
    const int tid = threadIdx.x;
    const int l = blockIdx.x;
#pragma unroll
    for (int i = 0; i < 4; ++i)
        *(float4v*)&Ws[tid * 4 + i * 1024] = *(const float4v*)&Wsx[tid * 4 + i * 1024];
    if (tid < 64) bs[tid] = bsx[tid];
    {
        const int bhh = tid >> 2, dq = (tid & 3) * 16;
        const unsigned short* src = &xh[((size_t)bhh * 1024 + l) * 64 + dq];
        *(short8v*)&Xl[bhh * 64 + dq] = *(const short8v*)src;
        *(short8v*)&Xl[bhh * 64 + dq + 8] = *(const short8v*)(src + 8);
    }
    __syncthreads();
    const int bh = tid >> 2, e0 = (tid & 3) * 16;
    float acc[16] = {};
    float bacc = 0.f;
    for (int d = 0; d < 64; ++d) {
        const float xd = b2f(Xl[bh * 64 + d]);
        bacc += xd * bs[d];
        const float* wr = &Ws[d * 64 + e0];
#pragma unroll
        for (int e = 0; e < 16; e += 4) {
            float4v w = *(const float4v*)&wr[e];
            acc[e] += xd * w[0]; acc[e + 1] += xd * w[1];
            acc[e + 2] += xd * w[2]; acc[e + 3] += xd * w[3];
        }
    }
    short8v p0, p1;
#pragma unroll
    for (int e = 0; e < 8; ++e) { p0[e] = (short)f2b(acc[e]); p1[e] = (short)f2b(acc[e + 8]); }
    unsigned short* dst = &x2b[((size_t)l * 64 + bh) * 64 + e0];
    *(short8v*)dst = p0; *(short8v*)(dst + 8) = p1;
    if ((tid & 3) == 0) xbv[l * 64 + bh] = bacc;
}

// ---------------------------------------------------------------------------
// P4-probe: ABLATION — staging + T3 + t3g dump + t3g readback ONLY.
// Identical code paths to struct_fused minus the T2 phase (q2b loads, T2
// MFMAs, T2 Ssh reads, qbv, sb stores). Writes a checksum to `dummy`
// (the scores region, fully overwritten by flash afterwards).
//   t_probe = total_R10 - total_R9  ->  localizes the struct_fused wall.
// ---------------------------------------------------------------------------
__global__ __launch_bounds__(256, 4) void struct_probe(
    const float* __restrict__ S,
    const unsigned short* __restrict__ k2b,
    const float* __restrict__ kbv,
    float* __restrict__ dummy) {
    __shared__ __align__(16) unsigned short Ssh[256 * 64];       // 32 KB
    __shared__ __align__(16) unsigned short t3g[4][4][16][16];   // 8 KB
    const int tid = threadIdx.x;
    const int w = tid >> 6, lane = tid & 63;
    const int lrow = lane & 15, g = lane >> 4;
    const int g8 = g << 3, row4 = g << 2;
    const int w16 = w << 4;
    const int r0 = blockIdx.x << 4, l0 = blockIdx.y << 4;

    {
        const int u = tid & 15, roff = tid >> 4;
        const float* gp = S + ((size_t)l0 * 1024 + r0 + roff) * 64 + u * 4;
        float4v f[16];
#pragma unroll
        for (int i = 0; i < 16; ++i)
            f[i] = *(const float4v*)(gp + (size_t)i * 65536);
#pragma unroll
        for (int i = 0; i < 16; ++i) {
            const int R = (i << 4) + roff;
            const int K3 = (roff ^ i) & 7;
            const int pu = u ^ (K3 << 1);
            union { unsigned uu[2]; uint2v v2; } o;
            asm("v_cvt_pk_bf16_f32 %0, %1, %2" : "=v"(o.uu[0]) : "v"(f[i][0]), "v"(f[i][1]));
            asm("v_cvt_pk_bf16_f32 %0, %1, %2" : "=v"(o.uu[1]) : "v"(f[i][2]), "v"(f[i][3]));
            *(uint2v*)&Ssh[(R << 6) + (pu << 2)] = o.v2;
        }
    }
    float kbreg[4];
#pragma unroll
    for (int j = 0; j < 4; ++j)
        kbreg[j] = kbv[(size_t)(r0 + row4 + j) * 64 + w16 + lrow];
    __syncthreads();

    float4v c3[16];
#pragma unroll
    for (int ri = 0; ri < 16; ++ri) {
        const int row = lrow * 16 + ri;
        const int key = (lrow ^ ri) & 7;
        short8v a0 = *(const short8v*)&Ssh[row * 64 + ((g ^ key) << 3)];
        short8v a1 = *(const short8v*)&Ssh[row * 64 + (((4 + g) ^ key) << 3)];
        const unsigned short* Bp = k2b + ((size_t)(r0 + ri) * 64 + w16 + lrow) * 64 + g8;
        short8v b0 = *(const short8v*)Bp;
        short8v b1 = *(const short8v*)(Bp + 32);
        float4v acc = {};
        acc = MFMA16(a0, b0, acc);
        acc = MFMA16(a1, b1, acc);
        c3[ri] = acc;
    }

    float4v chk = {};
#pragma unroll
    for (int G = 0; G < 4; ++G) {
        if (g == G) {
#pragma unroll
            for (int j = 0; j < 4; ++j) {
                float4v la{c3[0][j], c3[1][j], c3[2][j], c3[3][j]};
                float4v lb{c3[4][j], c3[5][j], c3[6][j], c3[7][j]};
                float4v ha{c3[8][j], c3[9][j], c3[10][j], c3[11][j]};
                float4v hb{c3[12][j], c3[13][j], c3[14][j], c3[15][j]};
                *(short8v*)&t3g[w][j][lrow][0] = pack8(la, lb);
                *(short8v*)&t3g[w][j][lrow][8] = pack8(ha, hb);
            }
        }
        asm volatile("s_waitcnt lgkmcnt(0)" ::: "memory");
#pragma unroll
        for (int lj = 0; lj < 4; ++lj) {
            short4v t3v = *(const short4v*)&t3g[w][lj][lrow][row4];
#pragma unroll
            for (int j = 0; j < 4; ++j)
                chk[j] += b2f((unsigned short)t3v[j]) + kbreg[j];
        }
    }
    *(float4v*)&dummy[(((size_t)blockIdx.y * 64 + blockIdx.x) * 256 + tid) * 4] = chk;
}

// ---------------------------------------------------------------------------
// P4 v9 (UNCHANGED from R9 — baseline for the subtraction)
// ---------------------------------------------------------------------------
__global__ __launch_bounds__(256, 4) void struct_fused(
    const float* __restrict__ S,              // [1024][1024][64] f32
    const unsigned short* __restrict__ q2b,   // [1024][64][64] bf16
    const unsigned short* __restrict__ k2b,   // [1024][64][64] bf16
    const float* __restrict__ qbv,            // [1024][64]
    const float* __restrict__ kbv,            // [1024][64]
    unsigned short* __restrict__ sb) {        // [1024][64][1024] bf16
    __shared__ __align__(16) unsigned short Ssh[256 * 64];       // 32 KB
    __shared__ __align__(16) unsigned short t3g[4][4][16][16];   // 8 KB
    const int tid = threadIdx.x;
    const int w = tid >> 6, lane = tid & 63;
    const int lrow = lane & 15, g = lane >> 4;
    const int g8 = g << 3, row4 = g << 2;
    const int w16 = w << 4;
    const int r0 = blockIdx.x << 4, l0 = blockIdx.y << 4;

    {
        const int u = tid & 15, roff = tid >> 4;
        const float* gp = S + ((size_t)l0 * 1024 + r0 + roff) * 64 + u * 4;
        float4v f[16];
#pragma unroll
        for (int i = 0; i < 16; ++i)
            f[i] = *(const float4v*)(gp + (size_t)i * 65536);   // +l -> +1024*64
#pragma unroll
        for (int i = 0; i < 16; ++i) {
            const int R = (i << 4) + roff;
            const int K3 = (roff ^ i) & 7;            // (R ^ R>>4) & 7
            const int pu = u ^ (K3 << 1);
            union { unsigned uu[2]; uint2v v2; } o;
            asm("v_cvt_pk_bf16_f32 %0, %1, %2" : "=v"(o.uu[0]) : "v"(f[i][0]), "v"(f[i][1]));
            asm("v_cvt_pk_bf16_f32 %0, %1, %2" : "=v"(o.uu[1]) : "v"(f[i][2]), "v"(f[i][3]));
            *(uint2v*)&Ssh[(R << 6) + (pu << 2)] = o.v2;
        }
    }
    float kbreg[4];
#pragma unroll
    for (int j = 0; j < 4; ++j)
        kbreg[j] = kbv[(size_t)(r0 + row4 + j) * 64 + w16 + lrow];
    __syncthreads();

    float4v c3[16];
#pragma unroll
    for (int ri = 0; ri < 16; ++ri) {
        const int row = lrow * 16 + ri;
        const int key = (lrow ^ ri) & 7;
        short8v a0 = *(const short8v*)&Ssh[row * 64 + ((g ^ key) << 3)];
        short8v a1 = *(const short8v*)&Ssh[row * 64 + (((4 + g) ^ key) << 3)];
        const unsigned short* Bp = k2b + ((size_t)(r0 + ri) * 64 + w16 + lrow) * 64 + g8;
        short8v b0 = *(const short8v*)Bp;
        short8v b1 = *(const short8v*)(Bp + 32);
        float4v acc = {};
        acc = MFMA16(a0, b0, acc);
        acc = MFMA16(a1, b1, acc);
        c3[ri] = acc;
    }

#pragma unroll
    for (int G = 0; G < 4; ++G) {
        if (g == G) {
#pragma unroll
            for (int j = 0; j < 4; ++j) {
                float4v la{c3[0][j], c3[1][j], c3[2][j], c3[3][j]};
                float4v lb{c3[4][j], c3[5][j], c3[6][j], c3[7][j]};
                float4v ha{c3[8][j], c3[9][j], c3[10][j], c3[11][j]};
                float4v hb{c3[12][j], c3[13][j], c3[14][j], c3[15][j]};
                *(short8v*)&t3g[w][j][lrow][0] = pack8(la, lb);
                *(short8v*)&t3g[w][j][lrow][8] = pack8(ha, hb);
            }
        }
        asm volatile("s_waitcnt lgkmcnt(0)" ::: "memory");
#pragma unroll
        for (int lj = 0; lj < 4; ++lj) {
            const int li = (G << 2) + lj;
            const int row = li * 16 + lrow;
            const int key = (li ^ lrow) & 7;
            short8v a0 = *(const short8v*)&Ssh[row * 64 + ((g ^ key) << 3)];
            short8v a1 = *(const short8v*)&Ssh[row * 64 + (((4 + g) ^ key) << 3)];
            const unsigned short* Bp = q2b + ((size_t)(l0 + li) * 64 + w16 + lrow) * 64 + g8;
            short8v b0 = *(const short8v*)Bp;
            short8v b1 = *(const short8v*)(Bp + 32);
            float4v c2 = {};
            c2 = MFMA16(a0, b0, c2);
            c2 = MFMA16(a1, b1, c2);
            short4v t3v = *(const short4v*)&t3g[w][lj][lrow][row4];
            const float qb = qbv[(size_t)(l0 + li) * 64 + w16 + lrow];
            short4v outv;
#pragma unroll
            for (int j = 0; j < 4; ++j)
                outv[j] = (short)f2b(c2[j] + b2f((unsigned short)t3v[j]) + qb + kbreg[j]);
            *(short4v*)&sb[((size_t)(l0 + li) * 64 + w16 + lrow) * 1024 + r0 + row4] = outv;
        }
    }
}

// ---------------------------------------------------------------------------
// P6: flash (unchanged)
// ---------------------------------------------------------------------------
__global__ __launch_bounds__(256) void flash_kernel(
    const unsigned short* __restrict__ qh,  // [64][1024][64] bf16
    const unsigned short* __restrict__ kh,
    const unsigned short* __restrict__ vT,  // [64][64][1024] bf16
    const unsigned short* __restrict__ sb,  // [1024][64][1024] bf16
    const float* __restrict__ mask,         // [4][1024]
    float* __restrict__ scores,             // [64][1024][1024]
    float* __restrict__ ctx) {              // [4][1024][1024]
    __shared__ __align__(16) float scL[32 * 64];
    __shared__ __align__(16) unsigned short pL[32 * 64];
    __shared__ float mL[32], sL[32], fL[32];
    const int bid = blockIdx.x;
    const int virt = (bid & 7) * 256 + (bid >> 3);
    const int bh = virt >> 5, lt = virt & 31;
    const int b = bh >> 4, h = bh & 15, l0 = lt * 32;
    const int tid = threadIdx.x, wave = tid >> 6, lane = tid & 63;
    const int lrow = lane & 15, g8 = (lane >> 4) << 3, row4 = (lane >> 4) << 2;
    short8v qf[2][2];
#pragma unroll
    for (int mt = 0; mt < 2; ++mt)
#pragma unroll
        for (int ks = 0; ks < 2; ++ks)
            qf[mt][ks] = *(const short8v*)&qh[((size_t)bh * 1024 + l0 + mt * 16 + lrow) * 64 + ks * 32 + g8];
    float4v opv[2] = {};
    if (tid < 32) { mL[tid] = -3e38f; sL[tid] = 0.f; }
    __syncthreads();
    const int tl = tid >> 3, tr8 = tid & 7;
    const int keyS = ((tl >> 2) & 3) << 4;
    const int keyP = (tl & 7) << 3;
    for (int rt = 0; rt < 16; ++rt) {
        const int r0 = rt * 64;
        float4v sacc[2] = {};
#pragma unroll
        for (int ks = 0; ks < 2; ++ks) {
            short8v kf = *(const short8v*)&kh[((size_t)bh * 1024 + r0 + wave * 16 + lrow) * 64 + ks * 32 + g8];
            sacc[0] = MFMA16(qf[0][ks], kf, sacc[0]);
            sacc[1] = MFMA16(qf[1][ks], kf, sacc[1]);
        }
#pragma unroll
        for (int mt = 0; mt < 2; ++mt)
#pragma unroll
            for (int j = 0; j < 4; ++j) {
                const int ll = mt * 16 + row4 + j;
                const int cc = wave * 16 + lrow;
                scL[ll * 64 + (cc ^ (((ll >> 2) & 3) << 4))] = sacc[mt][j];
            }
        __syncthreads();
        float4v x0 = *(const float4v*)&scL[tl * 64 + ((tr8 * 8) ^ keyS)];
        float4v x1 = *(const float4v*)&scL[tl * 64 + ((tr8 * 8 + 4) ^ keyS)];
        short8v sbv = *(const short8v*)&sb[((size_t)(l0 + tl) * 64 + bh) * 1024 + r0 + tr8 * 8];
        float4v mk0 = *(const float4v*)&mask[(size_t)b * 1024 + r0 + tr8 * 8];
        float4v mk1 = *(const float4v*)&mask[(size_t)b * 1024 + r0 + tr8 * 8 + 4];
        float s8[8];
#pragma unroll
        for (int i = 0; i < 4; ++i) {
            s8[i]     = (x0[i] + b2f((unsigned short)sbv[i])) * 0.125f + mk0[i];
            s8[i + 4] = (x1[i] + b2f((unsigned short)sbv[i + 4])) * 0.125f + mk1[i];
        }
        {
            float4v o0, o1;
#pragma unroll
            for (int i = 0; i < 4; ++i) { o0[i] = s8[i]; o1[i] = s8[i + 4]; }
            float* sgp = &scores[((size_t)bh * 1024 + l0 + tl) * 1024 + r0 + tr8 * 8];
            *(float4v*)sgp = o0; *(float4v*)(sgp + 4) = o1;
        }
        float tm = s8[0];
#pragma unroll
        for (int i = 1; i < 8; ++i) tm = fmaxf(tm, s8[i]);
        tm = fmaxf(tm, __shfl_xor(tm, 1));
        tm = fmaxf(tm, __shfl_xor(tm, 2));
        tm = fmaxf(tm, __shfl_xor(tm, 4));
        const float mold = mL[tl];
        const float mnew = fmaxf(mold, tm);
        const float f = __expf(mold - mnew);
        float psum = 0.f;
        float p8[8];
#pragma unroll
        for (int i = 0; i < 8; ++i) { p8[i] = __expf(s8[i] - mnew); psum += p8[i]; }
        psum += __shfl_xor(psum, 1);
        psum += __shfl_xor(psum, 2);
        psum += __shfl_xor(psum, 4);
        if (tr8 == 0) { sL[tl] = sL[tl] * f + psum; mL[tl] = mnew; fL[tl] = f; }
        short8v pk;
#pragma unroll
        for (int i = 0; i < 8; ++i) pk[i] = (short)f2b(p8[i]);
        *(short8v*)&pL[tl * 64 + ((tr8 * 8) ^ keyP)] = pk;
        __syncthreads();
#pragma unroll
        for (int mt = 0; mt < 2; ++mt)
#pragma unroll
            for (int j = 0; j < 4; ++j) opv[mt][j] *= fL[mt * 16 + row4 + j];
#pragma unroll
        for (int ks = 0; ks < 2; ++ks) {
            short8v pf0 = *(const short8v*)&pL[(lrow) * 64 + ((ks * 32 + g8) ^ ((lrow & 7) << 3))];
            short8v pf1 = *(const short8v*)&pL[(16 + lrow) * 64 + ((ks * 32 + g8) ^ ((lrow & 7) << 3))];
            short8v vf = *(const short8v*)&vT[((size_t)bh * 64 + wave * 16 + lrow) * 1024 + r0 + ks * 32 + g8];
            opv[0] = MFMA16(pf0, vf, opv[0]);
            opv[1] = MFMA16(pf1, vf, opv[1]);
        }
    }
#pragma unroll
    for (int mt = 0; mt < 2; ++mt)
#pragma unroll
        for (int j = 0; j < 4; ++j) {
            const int l = mt * 16 + row4 + j;
            const float inv = 1.f / sL[l];
            const int d = wave * 16 + lrow;
            ctx[((size_t)b * 1024 + l0 + l) * 1024 + h * 64 + d] = opv[mt][j] * inv;
        }
}

// ---------------------------------------------------------------------------
extern "C" void kernel_launch(void* const* d_in, const int* in_sizes, int n_in,
                              void* d_out, int out_size, void* d_ws, size_t ws_size,
                              hipStream_t stream) {
    (void)in_sizes; (void)n_in; (void)out_size; (void)ws_size;
    const float* hidden = (const float*)d_in[0];
    const float* mask   = (const float*)d_in[1];
    const float* S      = (const float*)d_in[2];
    const float* Wq  = (const float*)d_in[3];  const float* bq  = (const float*)d_in[4];
    const float* Wk  = (const float*)d_in[5];  const float* bk  = (const float*)d_in[6];
    const float* Wv  = (const float*)d_in[7];  const float* bv  = (const float*)d_in[8];
    const float* Wsq = (const float*)d_in[9];  const float* bsq = (const float*)d_in[10];
    const float* Wsk = (const float*)d_in[11]; const float* bsk = (const float*)d_in[12];

    float* ctx    = (float*)d_out;
    float* scores = ctx + (size_t)4 * 1024 * 1024;

    char* ws = (char*)d_ws;
    unsigned short* sbuf = (unsigned short*)ws;                 // [1024][64][1024] bf16, 128 MB
    unsigned short* hb  = (unsigned short*)ws;                  // stage-1 temps alias sbuf
    unsigned short* Wqb = (unsigned short*)(ws + (8u << 20));
    unsigned short* Wkb = (unsigned short*)(ws + (10u << 20));
    unsigned short* Wvb = (unsigned short*)(ws + (12u << 20));
    unsigned short* qh  = (unsigned short*)(ws + (size_t)(128u) * 1024 * 1024);
    unsigned short* kh  = qh  + (size_t)4 * 1024 * 1024;
    unsigned short* vT  = kh  + (size_t)4 * 1024 * 1024;
    unsigned short* q2b = vT  + (size_t)4 * 1024 * 1024;
    unsigned short* k2b = q2b + (size_t)4 * 1024 * 1024;
    float* qbv = (float*)(k2b + (size_t)4 * 1024 * 1024);
    float* kbv = qbv + 65536;

    pack_all<<<3584, 256, 0, stream>>>(hidden, Wq, Wk, Wv, hb, Wqb, Wkb, Wvb);
    qkv_gemm<<<dim3(16, 32), 256, 0, stream>>>(hb, Wqb, bq, qh, 0);
    qkv_gemm<<<dim3(16, 32), 256, 0, stream>>>(hb, Wkb, bk, kh, 0);
    qkv_gemm<<<dim3(16, 32), 256, 0, stream>>>(hb, Wvb, bv, vT, 1);
    headproj<<<1024, 256, 0, stream>>>(qh, Wsq, bsq, q2b, qbv);
    headproj<<<1024, 256, 0, stream>>>(kh, Wsk, bsk, k2b, kbv);
    // ABLATION PROBE: stage+T3 only; writes checksum into scores region
    // (flash fully overwrites scores afterwards).
    struct_probe<<<dim3(64, 64), 256, 0, stream>>>(S, k2b, kbv, scores);
    struct_fused<<<dim3(64, 64), 256, 0, stream>>>(S, q2b, k2b, qbv, kbv, sbuf);
    flash_kernel<<<2048, 256, 0, stream>>>(qh, kh, vT, sbuf, mask, scores, ctx);
}

// Round 11
// 526.687 us; speedup vs baseline: 1.1977x; 1.1977x over previous
//
#include <hip/hip_runtime.h>

typedef __attribute__((ext_vector_type(8))) short short8v;
typedef __attribute__((ext_vector_type(4))) short short4v;
typedef __attribute__((ext_vector_type(4))) float float4v;
typedef __attribute__((ext_vector_type(2))) unsigned int uint2v;

#define MFMA16(a,b,c) __builtin_amdgcn_mfma_f32_16x16x32_bf16(a,b,c,0,0,0)

__device__ __forceinline__ unsigned short f2b(float f) {
    union { float f; unsigned u; } v; v.f = f;
    unsigned r = v.u + 0x7FFFu + ((v.u >> 16) & 1u);
    return (unsigned short)(r >> 16);
}
__device__ __forceinline__ float b2f(unsigned short s) {
    union { unsigned u; float f; } v; v.u = ((unsigned)s) << 16;
    return v.f;
}
// RNE f32x8 -> bf16x8 via v_cvt_pk_bf16_f32 (same rounding as f2b)
__device__ __forceinline__ short8v pack8(float4v a, float4v b) {
    union { unsigned u[4]; short8v s; } o;
    asm("v_cvt_pk_bf16_f32 %0, %1, %2" : "=v"(o.u[0]) : "v"(a[0]), "v"(a[1]));
    asm("v_cvt_pk_bf16_f32 %0, %1, %2" : "=v"(o.u[1]) : "v"(a[2]), "v"(a[3]));
    asm("v_cvt_pk_bf16_f32 %0, %1, %2" : "=v"(o.u[2]) : "v"(b[0]), "v"(b[1]));
    asm("v_cvt_pk_bf16_f32 %0, %1, %2" : "=v"(o.u[3]) : "v"(b[2]), "v"(b[3]));
    return o.s;
}

// ---------------------------------------------------------------------------
// P1: consolidated f32 -> bf16 pack for hidden / Wq / Wk / Wv (one launch).
// ---------------------------------------------------------------------------
__global__ __launch_bounds__(256) void pack_all(
    const float* __restrict__ hidden, const float* __restrict__ Wq,
    const float* __restrict__ Wk, const float* __restrict__ Wv,
    unsigned short* __restrict__ hb, unsigned short* __restrict__ Wqb,
    unsigned short* __restrict__ Wkb, unsigned short* __restrict__ Wvb) {
    const int bid = blockIdx.x;
    const float* in; unsigned short* out; int i;
    if (bid < 2048)      { in = hidden; out = hb;  i = bid * 256 + threadIdx.x; }
    else if (bid < 2560) { in = Wq; out = Wqb; i = (bid - 2048) * 256 + threadIdx.x; }
    else if (bid < 3072) { in = Wk; out = Wkb; i = (bid - 2560) * 256 + threadIdx.x; }
    else                 { in = Wv; out = Wvb; i = (bid - 3072) * 256 + threadIdx.x; }
    float4v a = *(const float4v*)&in[(size_t)i * 8];
    float4v b = *(const float4v*)&in[(size_t)i * 8 + 4];
    *(short8v*)&out[(size_t)i * 8] = pack8(a, b);
}

// ---------------------------------------------------------------------------
// P2: C = hb @ W^T + bias  (MFMA bf16, operands direct from global)
// ---------------------------------------------------------------------------
__global__ __launch_bounds__(256) void qkv_gemm(
    const unsigned short* __restrict__ A,   // [4096][1024] bf16
    const unsigned short* __restrict__ W,   // [1024][1024] bf16 [n][k]
    const float* __restrict__ bias,         // [1024]
    unsigned short* __restrict__ out, int vmode) {
    const int wave = threadIdx.x >> 6, lane = threadIdx.x & 63;
    const int m0 = blockIdx.y * 128 + wave * 32;
    const int n0 = blockIdx.x * 64;
    const int lrow = lane & 15, g8 = (lane >> 4) << 3, row4 = (lane >> 4) << 2;
    float4v acc[2][4] = {};
    const unsigned short* Ap = A + (size_t)(m0 + lrow) * 1024 + g8;
    const unsigned short* Wp = W + (size_t)(n0 + lrow) * 1024 + g8;
#pragma unroll 2
    for (int k0 = 0; k0 < 1024; k0 += 32) {
        short8v a0 = *(const short8v*)(Ap + k0);
        short8v a1 = *(const short8v*)(Ap + 16 * 1024 + k0);
        short8v b0 = *(const short8v*)(Wp + k0);
        short8v b1 = *(const short8v*)(Wp + 16 * 1024 + k0);
        short8v b2 = *(const short8v*)(Wp + 32 * 1024 + k0);
        short8v b3 = *(const short8v*)(Wp + 48 * 1024 + k0);
        acc[0][0] = MFMA16(a0, b0, acc[0][0]); acc[0][1] = MFMA16(a0, b1, acc[0][1]);
        acc[0][2] = MFMA16(a0, b2, acc[0][2]); acc[0][3] = MFMA16(a0, b3, acc[0][3]);
        acc[1][0] = MFMA16(a1, b0, acc[1][0]); acc[1][1] = MFMA16(a1, b1, acc[1][1]);
        acc[1][2] = MFMA16(a1, b2, acc[1][2]); acc[1][3] = MFMA16(a1, b3, acc[1][3]);
    }
#pragma unroll
    for (int nt = 0; nt < 4; ++nt) {
        const int n = n0 + nt * 16 + lrow;           // C col = lane&15
        const float bz = bias[n];
        const int h = n >> 6, d = n & 63;
#pragma unroll
        for (int mt = 0; mt < 2; ++mt) {
            const int mb = m0 + mt * 16 + row4;      // C row = (lane>>4)*4 + j
            if (vmode == 0) {
#pragma unroll
                for (int j = 0; j < 4; ++j) {
                    const int m = mb + j;
                    const int b = m >> 10, l = m & 1023;
                    out[(((size_t)(b * 16 + h) << 10) + l) * 64 + d] = f2b(acc[mt][nt][j] + bz);
                }
            } else {
                const int b = mb >> 10, r = mb & 1023;
                short4v pk;
#pragma unroll
                for (int j = 0; j < 4; ++j) pk[j] = (short)f2b(acc[mt][nt][j] + bz);
                *(short4v*)&out[((((size_t)(b * 16 + h)) << 6) + d) * 1024 + r] = pk;
            }
        }
    }
}

// ---------------------------------------------------------------------------
// P3: headproj
// ---------------------------------------------------------------------------
__global__ __launch_bounds__(256) void headproj(
    const unsigned short* __restrict__ xh,  // [64][1024][64] bf16
    const float* __restrict__ Wsx,          // [64][64] f32
    const float* __restrict__ bsx,          // [64]
    unsigned short* __restrict__ x2b,       // [1024][64][64] bf16
    float* __restrict__ xbv) {              // [1024][64]
    __shared__ __align__(16) float Ws[64 * 64];
    __shared__ float bs[64];
    __shared__ __align__(16) unsigned short Xl[64 * 64];
    const int tid = threadIdx.x;
    const int l = blockIdx.x;
#pragma unroll
    for (int i = 0; i < 4; ++i)
        *(float4v*)&Ws[tid * 4 + i * 1024] = *(const float4v*)&Wsx[tid * 4 + i * 1024];
    if (tid < 64) bs[tid] = bsx[tid];
    {
        const int bhh = tid >> 2, dq = (tid & 3) * 16;
        const unsigned short* src = &xh[((size_t)bhh * 1024 + l) * 64 + dq];
        *(short8v*)&Xl[bhh * 64 + dq] = *(const short8v*)src;
        *(short8v*)&Xl[bhh * 64 + dq + 8] = *(const short8v*)(src + 8);
    }
    __syncthreads();
    const int bh = tid >> 2, e0 = (tid & 3) * 16;
    float acc[16] = {};
    float bacc = 0.f;
    for (int d = 0; d < 64; ++d) {
        const float xd = b2f(Xl[bh * 64 + d]);
        bacc += xd * bs[d];
        const float* wr = &Ws[d * 64 + e0];
#pragma unroll
        for (int e = 0; e < 16; e += 4) {
            float4v w = *(const float4v*)&wr[e];
            acc[e] += xd * w[0]; acc[e + 1] += xd * w[1];
            acc[e + 2] += xd * w[2]; acc[e + 3] += xd * w[3];
        }
    }
    short8v p0, p1;
#pragma unroll
    for (int e = 0; e < 8; ++e) { p0[e] = (short)f2b(acc[e]); p1[e] = (short)f2b(acc[e + 8]); }
    unsigned short* dst = &x2b[((size_t)l * 64 + bh) * 64 + e0];
    *(short8v*)dst = p0; *(short8v*)(dst + 8) = p1;
    if ((tid & 3) == 0) xbv[l * 64 + bh] = bacc;
}

// ---------------------------------------------------------------------------
// P4 v10: v9 + XCD-chunked block remap for L2 residency.
// Grid 4096 1-D. Assuming consecutive blockIdx round-robins the 8 XCDs
// (T1/m157), XCD x owns r-tiles [8x, 8x+8) for ALL l-tiles (l outermost):
//   - k2b slice per XCD = 1 MB -> L2-resident across all 64 l-sweeps
//     (L3 traffic 512 MB -> ~8 MB)
//   - q2b[l-tile] slice 128 KB reused 8x within the XCD (512 -> 64 MB)
// If the bid->XCD mapping assumption is wrong this is a harmless permutation.
// ---------------------------------------------------------------------------
__global__ __launch_bounds__(256, 4) void struct_fused(
    const float* __restrict__ S,              // [1024][1024][64] f32
    const unsigned short* __restrict__ q2b,   // [1024][64][64] bf16
    const unsigned short* __restrict__ k2b,   // [1024][64][64] bf16
    const float* __restrict__ qbv,            // [1024][64]
    const float* __restrict__ kbv,            // [1024][64]
    unsigned short* __restrict__ sb) {        // [1024][64][1024] bf16
    __shared__ __align__(16) unsigned short Ssh[256 * 64];       // 32 KB
    __shared__ __align__(16) unsigned short t3g[4][4][16][16];   // 8 KB
    const int tid = threadIdx.x;
    const int w = tid >> 6, lane = tid & 63;
    const int lrow = lane & 15, g = lane >> 4;
    const int g8 = g << 3, row4 = g << 2;
    const int w16 = w << 4;
    // XCD-chunked remap: xcd = n&7 owns r-tiles [8*xcd, 8*xcd+8), l outer.
    const int n = blockIdx.x;
    const int xcd = n & 7;
    const int idx = n >> 3;                  // 0..511
    const int rt = (xcd << 3) | (idx & 7);   // r-tile 0..63
    const int lt = idx >> 3;                 // l-tile 0..63
    const int r0 = rt << 4, l0 = lt << 4;

    // ---- reg-staged S tile: f32 global -> cvt -> swizzled bf16 LDS ----
    {
        const int u = tid & 15, roff = tid >> 4;
        const float* gp = S + ((size_t)l0 * 1024 + r0 + roff) * 64 + u * 4;
        float4v f[16];
#pragma unroll
        for (int i = 0; i < 16; ++i)
            f[i] = *(const float4v*)(gp + (size_t)i * 65536);   // +l -> +1024*64
#pragma unroll
        for (int i = 0; i < 16; ++i) {
            const int R = (i << 4) + roff;
            const int K3 = (roff ^ i) & 7;            // (R ^ R>>4) & 7
            const int pu = u ^ (K3 << 1);
            union { unsigned uu[2]; uint2v v2; } o;
            asm("v_cvt_pk_bf16_f32 %0, %1, %2" : "=v"(o.uu[0]) : "v"(f[i][0]), "v"(f[i][1]));
            asm("v_cvt_pk_bf16_f32 %0, %1, %2" : "=v"(o.uu[1]) : "v"(f[i][2]), "v"(f[i][3]));
            *(uint2v*)&Ssh[(R << 6) + (pu << 2)] = o.v2;
        }
    }
    float kbreg[4];
#pragma unroll
    for (int j = 0; j < 4; ++j)
        kbreg[j] = kbv[(size_t)(r0 + row4 + j) * 64 + w16 + lrow];
    __syncthreads();

    // ---- T3: per ri, A rows = l (lane&15); B = k2[r0+ri][bh-group] ----
    float4v c3[16];
#pragma unroll
    for (int ri = 0; ri < 16; ++ri) {
        const int row = lrow * 16 + ri;
        const int key = (lrow ^ ri) & 7;
        short8v a0 = *(const short8v*)&Ssh[row * 64 + ((g ^ key) << 3)];
        short8v a1 = *(const short8v*)&Ssh[row * 64 + (((4 + g) ^ key) << 3)];
        const unsigned short* Bp = k2b + ((size_t)(r0 + ri) * 64 + w16 + lrow) * 64 + g8;
        short8v b0 = *(const short8v*)Bp;
        short8v b1 = *(const short8v*)(Bp + 32);
        float4v acc = {};
        acc = MFMA16(a0, b0, acc);
        acc = MFMA16(a1, b1, acc);
        c3[ri] = acc;
    }

    // ---- T2 in 4 li-groups; JIT dump of the matching T3 slice ----
#pragma unroll
    for (int G = 0; G < 4; ++G) {
        if (g == G) {
#pragma unroll
            for (int j = 0; j < 4; ++j) {
                float4v la{c3[0][j], c3[1][j], c3[2][j], c3[3][j]};
                float4v lb{c3[4][j], c3[5][j], c3[6][j], c3[7][j]};
                float4v ha{c3[8][j], c3[9][j], c3[10][j], c3[11][j]};
                float4v hb{c3[12][j], c3[13][j], c3[14][j], c3[15][j]};
                *(short8v*)&t3g[w][j][lrow][0] = pack8(la, lb);
                *(short8v*)&t3g[w][j][lrow][8] = pack8(ha, hb);
            }
        }
        asm volatile("s_waitcnt lgkmcnt(0)" ::: "memory");
#pragma unroll
        for (int lj = 0; lj < 4; ++lj) {
            const int li = (G << 2) + lj;
            const int row = li * 16 + lrow;
            const int key = (li ^ lrow) & 7;
            short8v a0 = *(const short8v*)&Ssh[row * 64 + ((g ^ key) << 3)];
            short8v a1 = *(const short8v*)&Ssh[row * 64 + (((4 + g) ^ key) << 3)];
            const unsigned short* Bp = q2b + ((size_t)(l0 + li) * 64 + w16 + lrow) * 64 + g8;
            short8v b0 = *(const short8v*)Bp;
            short8v b1 = *(const short8v*)(Bp + 32);
            float4v c2 = {};
            c2 = MFMA16(a0, b0, c2);
            c2 = MFMA16(a1, b1, c2);
            short4v t3v = *(const short4v*)&t3g[w][lj][lrow][row4];
            const float qb = qbv[(size_t)(l0 + li) * 64 + w16 + lrow];
            short4v outv;
#pragma unroll
            for (int j = 0; j < 4; ++j)
                outv[j] = (short)f2b(c2[j] + b2f((unsigned short)t3v[j]) + qb + kbreg[j]);
            *(short4v*)&sb[((size_t)(l0 + li) * 64 + w16 + lrow) * 1024 + r0 + row4] = outv;
        }
    }
}

// ---------------------------------------------------------------------------
// P6: flash (unchanged)
// ---------------------------------------------------------------------------
__global__ __launch_bounds__(256) void flash_kernel(
    const unsigned short* __restrict__ qh,  // [64][1024][64] bf16
    const unsigned short* __restrict__ kh,
    const unsigned short* __restrict__ vT,  // [64][64][1024] bf16
    const unsigned short* __restrict__ sb,  // [1024][64][1024] bf16
    const float* __restrict__ mask,         // [4][1024]
    float* __restrict__ scores,             // [64][1024][1024]
    float* __restrict__ ctx) {              // [4][1024][1024]
    __shared__ __align__(16) float scL[32 * 64];
    __shared__ __align__(16) unsigned short pL[32 * 64];
    __shared__ float mL[32], sL[32], fL[32];
    const int bid = blockIdx.x;
    const int virt = (bid & 7) * 256 + (bid >> 3);
    const int bh = virt >> 5, lt = virt & 31;
    const int b = bh >> 4, h = bh & 15, l0 = lt * 32;
    const int tid = threadIdx.x, wave = tid >> 6, lane = tid & 63;
    const int lrow = lane & 15, g8 = (lane >> 4) << 3, row4 = (lane >> 4) << 2;
    short8v qf[2][2];
#pragma unroll
    for (int mt = 0; mt < 2; ++mt)
#pragma unroll
        for (int ks = 0; ks < 2; ++ks)
            qf[mt][ks] = *(const short8v*)&qh[((size_t)bh * 1024 + l0 + mt * 16 + lrow) * 64 + ks * 32 + g8];
    float4v opv[2] = {};
    if (tid < 32) { mL[tid] = -3e38f; sL[tid] = 0.f; }
    __syncthreads();
    const int tl = tid >> 3, tr8 = tid & 7;
    const int keyS = ((tl >> 2) & 3) << 4;
    const int keyP = (tl & 7) << 3;
    for (int rt = 0; rt < 16; ++rt) {
        const int r0 = rt * 64;
        float4v sacc[2] = {};
#pragma unroll
        for (int ks = 0; ks < 2; ++ks) {
            short8v kf = *(const short8v*)&kh[((size_t)bh * 1024 + r0 + wave * 16 + lrow) * 64 + ks * 32 + g8];
            sacc[0] = MFMA16(qf[0][ks], kf, sacc[0]);
            sacc[1] = MFMA16(qf[1][ks], kf, sacc[1]);
        }
#pragma unroll
        for (int mt = 0; mt < 2; ++mt)
#pragma unroll
            for (int j = 0; j < 4; ++j) {
                const int ll = mt * 16 + row4 + j;
                const int cc = wave * 16 + lrow;
                scL[ll * 64 + (cc ^ (((ll >> 2) & 3) << 4))] = sacc[mt][j];
            }
        __syncthreads();
        float4v x0 = *(const float4v*)&scL[tl * 64 + ((tr8 * 8) ^ keyS)];
        float4v x1 = *(const float4v*)&scL[tl * 64 + ((tr8 * 8 + 4) ^ keyS)];
        short8v sbv = *(const short8v*)&sb[((size_t)(l0 + tl) * 64 + bh) * 1024 + r0 + tr8 * 8];
        float4v mk0 = *(const float4v*)&mask[(size_t)b * 1024 + r0 + tr8 * 8];
        float4v mk1 = *(const float4v*)&mask[(size_t)b * 1024 + r0 + tr8 * 8 + 4];
        float s8[8];
#pragma unroll
        for (int i = 0; i < 4; ++i) {
            s8[i]     = (x0[i] + b2f((unsigned short)sbv[i])) * 0.125f + mk0[i];
            s8[i + 4] = (x1[i] + b2f((unsigned short)sbv[i + 4])) * 0.125f + mk1[i];
        }
        {
            float4v o0, o1;
#pragma unroll
            for (int i = 0; i < 4; ++i) { o0[i] = s8[i]; o1[i] = s8[i + 4]; }
            float* sgp = &scores[((size_t)bh * 1024 + l0 + tl) * 1024 + r0 + tr8 * 8];
            *(float4v*)sgp = o0; *(float4v*)(sgp + 4) = o1;
        }
        float tm = s8[0];
#pragma unroll
        for (int i = 1; i < 8; ++i) tm = fmaxf(tm, s8[i]);
        tm = fmaxf(tm, __shfl_xor(tm, 1));
        tm = fmaxf(tm, __shfl_xor(tm, 2));
        tm = fmaxf(tm, __shfl_xor(tm, 4));
        const float mold = mL[tl];
        const float mnew = fmaxf(mold, tm);
        const float f = __expf(mold - mnew);
        float psum = 0.f;
        float p8[8];
#pragma unroll
        for (int i = 0; i < 8; ++i) { p8[i] = __expf(s8[i] - mnew); psum += p8[i]; }
        psum += __shfl_xor(psum, 1);
        psum += __shfl_xor(psum, 2);
        psum += __shfl_xor(psum, 4);
        if (tr8 == 0) { sL[tl] = sL[tl] * f + psum; mL[tl] = mnew; fL[tl] = f; }
        short8v pk;
#pragma unroll
        for (int i = 0; i < 8; ++i) pk[i] = (short)f2b(p8[i]);
        *(short8v*)&pL[tl * 64 + ((tr8 * 8) ^ keyP)] = pk;
        __syncthreads();
#pragma unroll
        for (int mt = 0; mt < 2; ++mt)
#pragma unroll
            for (int j = 0; j < 4; ++j) opv[mt][j] *= fL[mt * 16 + row4 + j];
#pragma unroll
        for (int ks = 0; ks < 2; ++ks) {
            short8v pf0 = *(const short8v*)&pL[(lrow) * 64 + ((ks * 32 + g8) ^ ((lrow & 7) << 3))];
            short8v pf1 = *(const short8v*)&pL[(16 + lrow) * 64 + ((ks * 32 + g8) ^ ((lrow & 7) << 3))];
            short8v vf = *(const short8v*)&vT[((size_t)bh * 64 + wave * 16 + lrow) * 1024 + r0 + ks * 32 + g8];
            opv[0] = MFMA16(pf0, vf, opv[0]);
            opv[1] = MFMA16(pf1, vf, opv[1]);
        }
    }
#pragma unroll
    for (int mt = 0; mt < 2; ++mt)
#pragma unroll
        for (int j = 0; j < 4; ++j) {
            const int l = mt * 16 + row4 + j;
            const float inv = 1.f / sL[l];
            const int d = wave * 16 + lrow;
            ctx[((size_t)b * 1024 + l0 + l) * 1024 + h * 64 + d] = opv[mt][j] * inv;
        }
}

// ---------------------------------------------------------------------------
extern "C" void kernel_launch(void* const* d_in, const int* in_sizes, int n_in,
                              void* d_out, int out_size, void* d_ws, size_t ws_size,
                              hipStream_t stream) {
    (void)in_sizes; (void)n_in; (void)out_size; (void)ws_size;
    const float* hidden = (const float*)d_in[0];
    const float* mask   = (const float*)d_in[1];
    const float* S      = (const float*)d_in[2];
    const float* Wq  = (const float*)d_in[3];  const float* bq  = (const float*)d_in[4];
    const float* Wk  = (const float*)d_in[5];  const float* bk  = (const float*)d_in[6];
    const float* Wv  = (const float*)d_in[7];  const float* bv  = (const float*)d_in[8];
    const float* Wsq = (const float*)d_in[9];  const float* bsq = (const float*)d_in[10];
    const float* Wsk = (const float*)d_in[11]; const float* bsk = (const float*)d_in[12];

    float* ctx    = (float*)d_out;
    float* scores = ctx + (size_t)4 * 1024 * 1024;

    char* ws = (char*)d_ws;
    unsigned short* sbuf = (unsigned short*)ws;                 // [1024][64][1024] bf16, 128 MB
    unsigned short* hb  = (unsigned short*)ws;                  // stage-1 temps alias sbuf
    unsigned short* Wqb = (unsigned short*)(ws + (8u << 20));
    unsigned short* Wkb = (unsigned short*)(ws + (10u << 20));
    unsigned short* Wvb = (unsigned short*)(ws + (12u << 20));
    unsigned short* qh  = (unsigned short*)(ws + (size_t)(128u) * 1024 * 1024);
    unsigned short* kh  = qh  + (size_t)4 * 1024 * 1024;
    unsigned short* vT  = kh  + (size_t)4 * 1024 * 1024;
    unsigned short* q2b = vT  + (size_t)4 * 1024 * 1024;
    unsigned short* k2b = q2b + (size_t)4 * 1024 * 1024;
    float* qbv = (float*)(k2b + (size_t)4 * 1024 * 1024);
    float* kbv = qbv + 65536;

    pack_all<<<3584, 256, 0, stream>>>(hidden, Wq, Wk, Wv, hb, Wqb, Wkb, Wvb);
    qkv_gemm<<<dim3(16, 32), 256, 0, stream>>>(hb, Wqb, bq, qh, 0);
    qkv_gemm<<<dim3(16, 32), 256, 0, stream>>>(hb, Wkb, bk, kh, 0);
    qkv_gemm<<<dim3(16, 32), 256, 0, stream>>>(hb, Wvb, bv, vT, 1);
    headproj<<<1024, 256, 0, stream>>>(qh, Wsq, bsq, q2b, qbv);
    headproj<<<1024, 256, 0, stream>>>(kh, Wsk, bsk, k2b, kbv);
    struct_fused<<<4096, 256, 0, stream>>>(S, q2b, k2b, qbv, kbv, sbuf);
    flash_kernel<<<2048, 256, 0, stream>>>(qh, kh, vT, sbuf, mask, scores, ctx);
}